// Round 13
// baseline (134.864 us; speedup 1.0000x reference)
//
#include <hip/hip_runtime.h>
#include <stdint.h>

// Problem constants: B=32, S=10, D=4096, K=8192
#define B_ 32
#define S_ 10
#define D_ 4096
#define K_ 8192
#define RPB 21                 // rows per batch in A: 10 pq + 10 pp + 1 qq
#define M_REAL (B_ * RPB)      // 672

#define BM 128
#define BN 128
#define BK 32
#define M_PAD_MF 768           // 6 tiles of 128
#define KSPLIT 2
#define KHALF (D_ / KSPLIT)    // 2048
#define NSTEP (KHALF / BK)     // 64

typedef _Float16 f16x8 __attribute__((ext_vector_type(8)));
typedef float f32x4 __attribute__((ext_vector_type(4)));
typedef unsigned short us4 __attribute__((ext_vector_type(4)));

__device__ __forceinline__ void async16(const void* g, void* l) {
  __builtin_amdgcn_global_load_lds(
      (const __attribute__((address_space(1))) unsigned int*)g,
      (__attribute__((address_space(3))) unsigned int*)l, 16, 0, 0);
}

// ---------------------------------------------------------------------------
// Prepass: build A rows (pq / pp / qq), quantize to a single f16 plane.
// ---------------------------------------------------------------------------
__global__ __launch_bounds__(256)
void build_a_f16(const float* __restrict__ p, const float* __restrict__ q,
                 unsigned short* __restrict__ Af) {
  size_t idx = (size_t)blockIdx.x * 256 + threadIdx.x;  // over M_PAD_MF * 1024 float4s
  int d4 = (int)(idx & 1023);
  int m = (int)(idx >> 10);
  float4 v = make_float4(0.f, 0.f, 0.f, 0.f);
  if (m < M_REAL) {
    int b = m / RPB;
    int r = m - b * RPB;
    const float4* q4 = (const float4*)(q + (size_t)(b * S_ + (S_ - 1)) * D_);
    if (r < S_) {
      const float4* p4 = (const float4*)(p + (size_t)(b * S_ + r) * D_);
      float4 pv = p4[d4]; float4 qv = q4[d4];
      v = make_float4(pv.x * qv.x, pv.y * qv.y, pv.z * qv.z, pv.w * qv.w);
    } else if (r < 2 * S_) {
      const float4* p4 = (const float4*)(p + (size_t)(b * S_ + (r - S_)) * D_);
      float4 pv = p4[d4];
      v = make_float4(pv.x * pv.x, pv.y * pv.y, pv.z * pv.z, pv.w * pv.w);
    } else {
      float4 qv = q4[d4];
      v = make_float4(qv.x * qv.x, qv.y * qv.y, qv.z * qv.z, qv.w * qv.w);
    }
  }
  us4 h;
  ((unsigned short*)&h)[0] = (unsigned short)__builtin_bit_cast(unsigned short, (_Float16)v.x);
  ((unsigned short*)&h)[1] = (unsigned short)__builtin_bit_cast(unsigned short, (_Float16)v.y);
  ((unsigned short*)&h)[2] = (unsigned short)__builtin_bit_cast(unsigned short, (_Float16)v.z);
  ((unsigned short*)&h)[3] = (unsigned short)__builtin_bit_cast(unsigned short, (_Float16)v.w);
  ((us4*)Af)[idx] = h;
}

// ---------------------------------------------------------------------------
// Fused MFMA GEMM: G[ks][m][k] = sum_{d in half ks} Af[m][d] * (W[k][d])^2
// T4 (counted vmcnt) applied to the R10 all-DMA body:
//   TRIPLE-buffered LDS, depth-2 prefetch: at step i issue the 6 DMA for
//   step i+2, compute step i, then  sched_barrier(0); s_waitcnt vmcnt(6);
//   s_barrier; sched_barrier(0).  The wait retires loads(i+1) while
//   loads(i+2) stay in flight ACROSS the barrier — vmcnt never drains to 0
//   in the main loop, each load gets ~2 full steps of latency hiding.
// Hazards: buf[(i+2)%3] was last read in step i-1 (reads consumed before
//   barrier(i-1) via compiler lgkm waits) -> WAR safe; all staging is DMA so
//   the manual vmcnt count (6/thread/step) is exact; the clamped tail stages
//   the same 6 ops into an unread buffer (count invariant, junk harmless).
//   A (f16): 2 DMA/thread/step.  W (f32): 4 DMA/thread/step, square+cvt at
//   FRAGMENT READ time (VALU co-issues with MFMA; no prepass, no ds_write).
// LDS 72 KB: A bufs 3x8K @0 | W bufs 3x16K @24K   -> 2 blocks/CU.
// Swizzles (involutions, on DMA source and frag reads):
//   A row = 64 B  = 4 granules:  phys = g ^ ((row ^ (row>>2)) & 3)
//   W row = 128 B = 8 granules:  phys = g ^ (row & 7)
// ---------------------------------------------------------------------------
__global__ __launch_bounds__(256)
void gemm_mfma(const unsigned short* __restrict__ Af, const float* __restrict__ W,
               float* __restrict__ G) {
  __shared__ unsigned short lds[36864];   // 72 KB
  const int tid = threadIdx.x;
  const int lane = tid & 63;
  const int wid = tid >> 6;
  const int m0 = blockIdx.y * BM;
  const int n0 = blockIdx.x * BN;
  const int ks = blockIdx.z;
  const int d_base = ks * KHALF;

  char* const ldsb = (char*)lds;          // A buffers: +0, +8192, +16384
  char* const ldsWf = ldsb + 24576;       // W buffers: +0, +16384, +32768

  // ---- A staging: 2 async DMA issues per k-step, pre-swizzled global src ----
  const unsigned short* gpA[2];
  uint32_t ldsoffA[2];
#pragma unroll
  for (int half = 0; half < 2; ++half) {
    int row = half * 64 + wid * 16 + (lane >> 2);
    int g = (lane & 3) ^ ((row ^ (row >> 2)) & 3);
    gpA[half] = Af + (size_t)(m0 + row) * D_ + d_base + g * 8;
    ldsoffA[half] = (uint32_t)(half * 4096 + wid * 1024);   // bytes
  }

  // ---- W staging: 4 async DMA issues per thread (16 KB fp32 tile) ----
  const float* gpW[4];
  uint32_t ldsoffW[4];
#pragma unroll
  for (int e = 0; e < 4; ++e) {
    int row = wid * 32 + e * 8 + (lane >> 3);
    int g = (lane & 7) ^ (row & 7);
    gpW[e] = W + (size_t)(n0 + row) * D_ + d_base + g * 4;
    ldsoffW[e] = (uint32_t)((wid * 4 + e) * 1024);
  }

  f32x4 acc[4][4];
#pragma unroll
  for (int i = 0; i < 4; ++i)
#pragma unroll
    for (int j = 0; j < 4; ++j) acc[i][j] = (f32x4){0.f, 0.f, 0.f, 0.f};

  const int wm = wid >> 1;        // wave row in 2x2 grid
  const int wn = wid & 1;
  const int frow = lane & 15;
  const int k16 = lane >> 4;
  int aoff[4];                    // A frag byte offsets
  int woffL[4], woffH[4];         // W frag lo/hi b128 byte offsets
#pragma unroll
  for (int f = 0; f < 4; ++f) {
    int ra = wm * 64 + f * 16 + frow;
    aoff[f] = ra * 64 + ((k16 ^ ((ra ^ (ra >> 2)) & 3)) * 16);
    int rw = wn * 64 + f * 16 + frow;
    woffL[f] = rw * 128 + (((2 * k16) ^ (rw & 7)) * 16);
    woffH[f] = rw * 128 + (((2 * k16 + 1) ^ (rw & 7)) * 16);
  }

  // ---- stage helper offsets per buffer slot ----
  // A slot b: ldsb + b*8192 ; W slot b: ldsWf + b*16384
#define STAGE_STEP(dstep, bslot)                                        \
  {                                                                     \
    const int _d = (dstep) * BK;                                        \
    char* _ab = ldsb + (bslot) * 8192;                                  \
    char* _wb = ldsWf + (bslot) * 16384;                                \
    async16(gpA[0] + _d, _ab + ldsoffA[0]);                             \
    async16(gpA[1] + _d, _ab + ldsoffA[1]);                             \
    async16(gpW[0] + _d, _wb + ldsoffW[0]);                             \
    async16(gpW[1] + _d, _wb + ldsoffW[1]);                             \
    async16(gpW[2] + _d, _wb + ldsoffW[2]);                             \
    async16(gpW[3] + _d, _wb + ldsoffW[3]);                             \
  }

  // ---- prologue: stage steps 0 and 1; wait only for step 0 (vmcnt(6)) ----
  STAGE_STEP(0, 0);
  STAGE_STEP(1, 1);
  __builtin_amdgcn_sched_barrier(0);
  asm volatile("s_waitcnt vmcnt(6)" ::: "memory");   // step-0 loads retired
  __builtin_amdgcn_s_barrier();
  __builtin_amdgcn_sched_barrier(0);

  for (int i = 0; i < NSTEP; ++i) {
    // ---- issue step i+2 into buf[(i+2)%3] (stays in flight across barrier) ----
    const int ds = (i + 2 < NSTEP) ? (i + 2) : (NSTEP - 1);   // clamped
    STAGE_STEP(ds, (i + 2) % 3);

    // ---- compute step i from buf[i%3] ----
    char* const cbA = ldsb + (i % 3) * 8192;
    char* const cbW = ldsWf + (i % 3) * 16384;
    f16x8 aF[4];
#pragma unroll
    for (int f = 0; f < 4; ++f)
      aF[f] = *(const f16x8*)(cbA + aoff[f]);
#pragma unroll
    for (int nf = 0; nf < 4; ++nf) {
      f32x4 lo = *(const f32x4*)(cbW + woffL[nf]);
      f32x4 hi = *(const f32x4*)(cbW + woffH[nf]);
      f16x8 wF;
      wF[0] = (_Float16)(lo[0] * lo[0]); wF[1] = (_Float16)(lo[1] * lo[1]);
      wF[2] = (_Float16)(lo[2] * lo[2]); wF[3] = (_Float16)(lo[3] * lo[3]);
      wF[4] = (_Float16)(hi[0] * hi[0]); wF[5] = (_Float16)(hi[1] * hi[1]);
      wF[6] = (_Float16)(hi[2] * hi[2]); wF[7] = (_Float16)(hi[3] * hi[3]);
#pragma unroll
      for (int mf = 0; mf < 4; ++mf)
        acc[mf][nf] = __builtin_amdgcn_mfma_f32_16x16x32_f16(aF[mf], wF, acc[mf][nf], 0, 0, 0);
    }

    // ---- counted-vmcnt barrier: loads(i+1) retired, loads(i+2) in flight ----
    __builtin_amdgcn_sched_barrier(0);
    asm volatile("s_waitcnt vmcnt(6)" ::: "memory");
    __builtin_amdgcn_s_barrier();
    __builtin_amdgcn_sched_barrier(0);
  }
#undef STAGE_STEP

  // ---- C write: row=(lane>>4)*4+r, col=lane&15 (verified gfx950 C/D layout) ----
  float* Gp = G + (size_t)ks * M_PAD_MF * K_;
  const int crow = m0 + wm * 64;
  const int ccol = n0 + wn * 64;
#pragma unroll
  for (int mf = 0; mf < 4; ++mf)
#pragma unroll
    for (int nf = 0; nf < 4; ++nf)
#pragma unroll
      for (int r = 0; r < 4; ++r) {
        int row = crow + mf * 16 + (lane >> 4) * 4 + r;
        int col = ccol + nf * 16 + (lane & 15);
        Gp[(size_t)row * K_ + col] = acc[mf][nf][r];
      }
}

// ---------------------------------------------------------------------------
// Epilogue: sum K-split planes, normalize, transpose-write.
// out[b][k][s] = -dot / (sqrt(pp)*sqrt(qq)*D)
// ---------------------------------------------------------------------------
__global__ __launch_bounds__(256)
void epilogue2(const float* __restrict__ G, float* __restrict__ out) {
  __shared__ float buf[256 * S_];
  const int tid = threadIdx.x;
  const int b = blockIdx.y;
  const int k0 = blockIdx.x * 256;
  const int k = k0 + tid;
  const float* G0 = G + (size_t)b * RPB * K_ + k;
  const float* G1 = G0 + (size_t)M_PAD_MF * K_;
  float nq = sqrtf(G0[20 * K_] + G1[20 * K_]);
#pragma unroll
  for (int s = 0; s < S_; ++s) {
    float dot = G0[s * K_] + G1[s * K_];
    float pp = G0[(S_ + s) * K_] + G1[(S_ + s) * K_];
    buf[tid * S_ + s] = -dot / (sqrtf(pp) * nq * (float)D_);
  }
  __syncthreads();
  float* ob = out + ((size_t)b * K_ + k0) * S_;
  for (int i = tid; i < 256 * S_; i += 256) ob[i] = buf[i];
}

// ===========================================================================
extern "C" void kernel_launch(void* const* d_in, const int* in_sizes, int n_in,
                              void* d_out, int out_size, void* d_ws, size_t ws_size,
                              hipStream_t stream) {
  const float* p = (const float*)d_in[0];
  const float* q = (const float*)d_in[1];
  const float* W = (const float*)d_in[2];
  float* out = (float*)d_out;

  // ws layout: Af [768][4096] f16 (6291456 B) | G [2][768][8192] f32 (50331648 B)
  uint8_t* w = (uint8_t*)d_ws;
  unsigned short* Af = (unsigned short*)w;
  float* G = (float*)(w + 6291456);

  build_a_f16<<<(M_PAD_MF * (D_ / 4)) / 256, 256, 0, stream>>>(p, q, Af);
  dim3 ggrid(K_ / BN, M_PAD_MF / BM, KSPLIT);   // (64, 6, 2) = 768 blocks
  gemm_mfma<<<ggrid, 256, 0, stream>>>(Af, W, G);
  epilogue2<<<dim3(K_ / 256, B_), 256, 0, stream>>>(G, out);
}